// Round 3
// baseline (2514.493 us; speedup 1.0000x reference)
//
#include <hip/hip_runtime.h>
#include <math.h>

#define T_ 512
#define B_ 64
#define V_ 50000
#define E_ 300
#define H_ 256
#define K_ 20
#define G4 1024  /* 4*H */

typedef float f4 __attribute__((ext_vector_type(4)));
typedef _Float16 h2_t __attribute__((ext_vector_type(2)));
union U32H2 { unsigned u; h2_t h; };
__device__ __forceinline__ h2_t u2h(unsigned u) { U32H2 x; x.u = u; return x.h; }
__device__ __forceinline__ unsigned h2u(h2_t h) { U32H2 x; x.h = h; return x.u; }

__device__ __forceinline__ float sigf(float x) { return 1.f / (1.f + __expf(-x)); }
__device__ __forceinline__ float tanhfast(float x) { return 1.f - 2.f / (__expf(2.f * x) + 1.f); }

__device__ __forceinline__ unsigned char f32_e4m3(float x) {
  return (unsigned char)(__builtin_amdgcn_cvt_pk_fp8_f32(x, x, 0, false) & 0xff);
}

// ---------------- prep: transpose w_ih, quantize w_hh to fp8 e4m3 (x64), biases, zero out ----
__global__ void prep_kernel(const float* __restrict__ w_ih, const float* __restrict__ w_hh,
                            const float* __restrict__ b_ih, const float* __restrict__ b_hh,
                            float* __restrict__ w_ihT, unsigned char* __restrict__ W8,
                            float* __restrict__ b_comb, float* __restrict__ out) {
  int tid = blockIdx.x * blockDim.x + threadIdx.x;
  int nth = gridDim.x * blockDim.x;
  for (int i = tid; i < E_ * G4; i += nth) {
    int e = i >> 10, row = i & 1023;
    w_ihT[i] = w_ih[row * E_ + e];
  }
  for (int i = tid; i < G4 * H_; i += nth) {
    W8[i] = f32_e4m3(w_hh[i] * 64.f);
  }
  for (int i = tid; i < G4; i += nth) b_comb[i] = b_ih[i] + b_hh[i];
  if (tid == 0) out[0] = 0.f;
}

// ---------------- kernel A: g_in[t][b][row] (f16) = emb[inp[t,b]] @ w_ih^T + b_ih + b_hh ------
__global__ __launch_bounds__(256) void kernelA(const int* __restrict__ inp,
                                               const float* __restrict__ emb,
                                               const float* __restrict__ w_ihT,
                                               const float* __restrict__ b_comb,
                                               unsigned* __restrict__ g_in_u) {
  __shared__ float xs[32][304];
  __shared__ int ridx[32];
  int bm = blockIdx.x >> 2;
  int bn = blockIdx.x & 3;
  int tid = threadIdx.x;
  if (tid < 32) ridx[tid] = inp[bm * 32 + tid];
  __syncthreads();
  for (int i = tid; i < 32 * 75; i += 256) {
    int r = i / 75, c = i % 75;
    float4 v = *(const float4*)(emb + (long)ridx[r] * E_ + c * 4);
    *(float4*)&xs[r][c * 4] = v;
  }
  __syncthreads();
  int cx = tid & 63, ry = tid >> 6;
  int col = bn * 256 + cx * 4;
  float4 acc[8];
#pragma unroll
  for (int r = 0; r < 8; r++) acc[r] = make_float4(0.f, 0.f, 0.f, 0.f);
#pragma unroll 4
  for (int e = 0; e < E_; e++) {
    float4 w = *(const float4*)(w_ihT + e * G4 + col);
#pragma unroll
    for (int r = 0; r < 8; r++) {
      float xv = xs[ry * 8 + r][e];
      acc[r].x += xv * w.x; acc[r].y += xv * w.y;
      acc[r].z += xv * w.z; acc[r].w += xv * w.w;
    }
  }
  float4 bb = *(const float4*)(b_comb + col);
#pragma unroll
  for (int r = 0; r < 8; r++) {
    float4 o = acc[r];
    o.x += bb.x; o.y += bb.y; o.z += bb.z; o.w += bb.w;
    h2_t p0, p1;
    p0.x = (_Float16)o.x; p0.y = (_Float16)o.y;
    p1.x = (_Float16)o.z; p1.y = (_Float16)o.w;
    uint2 st; st.x = h2u(p0); st.y = h2u(p1);
    long row = (long)bm * 32 + ry * 8 + r;
    *(uint2*)(g_in_u + ((row * G4 + col) >> 1)) = st;
  }
}

// ---------------- kernel B: sequential LSTM, fp8 MFMA, weights PINNED in registers -----------
// 16 blocks x 1024 threads (16 waves). Block bb owns batches 4bb..4bb+3.
// Wave w owns gate rows 16*(w+16*tau)+col for tau=i,f,g,o -> all 4 gates of units 16w..16w+15.
// B-fragment cols: col&3 (broadcast x4) so EVERY lane's accs hold valid gates -> in-register
// elementwise on all lanes; only col<4 lanes commit state. One barrier per step.
#define WSCALE 64.f
#define HSCALE 16.f
#define DESCALE (1.f / (WSCALE * HSCALE))

__global__ __launch_bounds__(1024, 4) void kernelB(const _Float16* __restrict__ g_in,
                                                   const unsigned char* __restrict__ W8,
                                                   float* __restrict__ houts) {
  int bb = blockIdx.x;
  int tid = threadIdx.x;
  int lane = tid & 63, w = tid >> 6;
  int col = lane & 15, quad = lane >> 4;
  int cb = col & 3;

  __shared__ unsigned char h8[2][4 * 272];   // [buf][batch][k-permuted 256 + pad]

  for (int i = tid; i < 2 * 4 * 272; i += 1024) ((unsigned char*)h8)[i] = 0;

  // persistent A-fragments: wf[tau*8+c] = W8[16*(w+16*tau)+col][32c + quad*8 .. +7]
  unsigned long long wf[32];
#pragma unroll
  for (int tc = 0; tc < 32; tc++) {
    int tau = tc >> 3, c = tc & 7;
    wf[tc] = *(const unsigned long long*)(W8 + (unsigned)(16 * (w + 16 * tau) + col) * 256 + quad * 8 + 32 * c);
  }
#pragma unroll
  for (int tc = 0; tc < 32; tc++) asm volatile("" : "+v"(wf[tc]));  // pin: no remat possible

  int u0 = 16 * w + 4 * quad;                 // this thread's 4 units: u0..u0+3
  int batch = 4 * bb + cb;
  const _Float16* gbase = g_in + (long)batch * G4 + u0;
  // h8 write slot (col<4 lanes): 4 consecutive bytes for units u0..u0+3
  int wslot = cb * 272 + ((2 * w + (quad >> 1)) & 3) * 64 + (w >> 1) * 8 + 4 * (quad & 1);
  const unsigned char* bp0 = &h8[0][cb * 272 + quad * 64];
  const unsigned char* bp1 = &h8[1][cb * 272 + quad * 64];

  float cst[4] = {0.f, 0.f, 0.f, 0.f};

  // preload g for t=0
  uint2 gi_ = *(const uint2*)(gbase + 0);
  uint2 gf_ = *(const uint2*)(gbase + 256);
  uint2 gg_ = *(const uint2*)(gbase + 512);
  uint2 go_ = *(const uint2*)(gbase + 768);

  __syncthreads();

  for (int t = 0; t < T_; t++) {
    const unsigned char* bptr = (t & 1) ? bp1 : bp0;
    f4 acc0 = {0.f, 0.f, 0.f, 0.f}, acc1 = acc0, acc2 = acc0, acc3 = acc0;
#pragma unroll
    for (int i = 0; i < 4; i++) {
      ulonglong2 bv = *(const ulonglong2*)(bptr + i * 16);
      long long b0 = (long long)bv.x;
      long long b1 = (long long)bv.y;
      acc0 = __builtin_amdgcn_mfma_f32_16x16x32_fp8_fp8((long long)wf[0 * 8 + 2 * i], b0, acc0, 0, 0, 0);
      acc1 = __builtin_amdgcn_mfma_f32_16x16x32_fp8_fp8((long long)wf[1 * 8 + 2 * i], b0, acc1, 0, 0, 0);
      acc2 = __builtin_amdgcn_mfma_f32_16x16x32_fp8_fp8((long long)wf[2 * 8 + 2 * i], b0, acc2, 0, 0, 0);
      acc3 = __builtin_amdgcn_mfma_f32_16x16x32_fp8_fp8((long long)wf[3 * 8 + 2 * i], b0, acc3, 0, 0, 0);
      acc0 = __builtin_amdgcn_mfma_f32_16x16x32_fp8_fp8((long long)wf[0 * 8 + 2 * i + 1], b1, acc0, 0, 0, 0);
      acc1 = __builtin_amdgcn_mfma_f32_16x16x32_fp8_fp8((long long)wf[1 * 8 + 2 * i + 1], b1, acc1, 0, 0, 0);
      acc2 = __builtin_amdgcn_mfma_f32_16x16x32_fp8_fp8((long long)wf[2 * 8 + 2 * i + 1], b1, acc2, 0, 0, 0);
      acc3 = __builtin_amdgcn_mfma_f32_16x16x32_fp8_fp8((long long)wf[3 * 8 + 2 * i + 1], b1, acc3, 0, 0, 0);
    }
    // prefetch next step's g while MFMAs drain
    int tn = (t + 1 < T_) ? (t + 1) : t;
    const _Float16* gp = gbase + (long)tn * B_ * G4;
    uint2 ngi = *(const uint2*)(gp + 0);
    uint2 ngf = *(const uint2*)(gp + 256);
    uint2 ngg = *(const uint2*)(gp + 512);
    uint2 ngo = *(const uint2*)(gp + 768);

    // in-register elementwise on all lanes (cols 4..15 are duplicates)
    h2_t gia = u2h(gi_.x), gib = u2h(gi_.y);
    h2_t gfa = u2h(gf_.x), gfb = u2h(gf_.y);
    h2_t gga = u2h(gg_.x), ggb = u2h(gg_.y);
    h2_t goa = u2h(go_.x), gob = u2h(go_.y);
    float giv[4] = {(float)gia.x, (float)gia.y, (float)gib.x, (float)gib.y};
    float gfv[4] = {(float)gfa.x, (float)gfa.y, (float)gfb.x, (float)gfb.y};
    float ggv[4] = {(float)gga.x, (float)gga.y, (float)ggb.x, (float)ggb.y};
    float gov[4] = {(float)goa.x, (float)goa.y, (float)gob.x, (float)gob.y};
    float h[4];
#pragma unroll
    for (int r = 0; r < 4; r++) {
      float gi = acc0[r] * DESCALE + giv[r];
      float gf = acc1[r] * DESCALE + gfv[r];
      float gg = acc2[r] * DESCALE + ggv[r];
      float go = acc3[r] * DESCALE + gov[r];
      cst[r] = sigf(gf) * cst[r] + sigf(gi) * tanhfast(gg);
      h[r] = sigf(go) * tanhfast(cst[r]);
    }
    if (col < 4) {
      uchar4 hq;
      hq.x = f32_e4m3(h[0] * HSCALE);
      hq.y = f32_e4m3(h[1] * HSCALE);
      hq.z = f32_e4m3(h[2] * HSCALE);
      hq.w = f32_e4m3(h[3] * HSCALE);
      *(uchar4*)&h8[1 - (t & 1)][wslot] = hq;
      *(float4*)(houts + ((long)t * B_ + batch) * H_ + u0) = make_float4(h[0], h[1], h[2], h[3]);
    }
    gi_ = ngi; gf_ = ngf; gg_ = ngg; go_ = ngo;
    __syncthreads();
  }
}

// ---------------- kernel C: emissions = houts @ W_lin^T + b_lin ------------------------------
__global__ __launch_bounds__(256) void kernelC(const float* __restrict__ houts,
                                               const float* __restrict__ W_lin,
                                               const float* __restrict__ b_lin,
                                               float* __restrict__ em) {
  __shared__ float hs[32][260];
  __shared__ float wl[20][260];
  __shared__ float bl[20];
  int bm = blockIdx.x;
  int tid = threadIdx.x;
  for (int i = tid; i < 32 * 64; i += 256) {
    int r = i >> 6, c = i & 63;
    *(float4*)&hs[r][c * 4] = *(const float4*)(houts + ((long)bm * 32 + r) * H_ + c * 4);
  }
  for (int i = tid; i < 20 * 64; i += 256) {
    int k = i >> 6, c = i & 63;
    *(float4*)&wl[k][c * 4] = *(const float4*)(W_lin + k * H_ + c * 4);
  }
  if (tid < 20) bl[tid] = b_lin[tid];
  __syncthreads();
  for (int o = tid; o < 32 * 20; o += 256) {
    int r = o / 20, k = o % 20;
    float s = 0.f;
#pragma unroll 4
    for (int i = 0; i < H_; i++) s += hs[r][i] * wl[k][i];
    em[(long)bm * 32 * K_ + o] = s + bl[k];
  }
}

// ---------------- kernel D: CRF forward DP + gold score + NLL reduction ----------------------
__global__ __launch_bounds__(64) void kernelD(const float* __restrict__ em,
                                              const int* __restrict__ labels,
                                              const float* __restrict__ start_t,
                                              const float* __restrict__ end_t,
                                              const float* __restrict__ trans,
                                              float* __restrict__ out) {
  int b = blockIdx.x;
  int k = threadIdx.x;
  __shared__ float tr[400];
  __shared__ float alpha[2][20];
  for (int i = k; i < 400; i += 64) tr[i] = trans[i];
  float score = 0.f;
  int prevtag = 0;
  if (k == 0) {
    int t0 = labels[b];
    score = start_t[t0] + em[b * K_ + t0];
    prevtag = t0;
  }
  if (k < K_) alpha[0][k] = start_t[k] + em[b * K_ + k];
  __syncthreads();
  int p = 0;
  for (int t = 1; t < T_; t++) {
    const float* emrow = em + ((long)t * B_ + b) * K_;
    if (k < K_) {
      float v[20];
      float m = -1e30f;
#pragma unroll
      for (int j = 0; j < 20; j++) {
        v[j] = alpha[p][j] + tr[j * 20 + k];
        m = fmaxf(m, v[j]);
      }
      float s = 0.f;
#pragma unroll
      for (int j = 0; j < 20; j++) s += __expf(v[j] - m);
      alpha[1 - p][k] = emrow[k] + m + __logf(s);
    }
    if (k == 0) {
      int tg = labels[t * B_ + b];
      score += tr[prevtag * 20 + tg] + emrow[tg];
      prevtag = tg;
    }
    p ^= 1;
    __syncthreads();
  }
  if (k == 0) {
    score += end_t[prevtag];
    float m = -1e30f;
    for (int j = 0; j < 20; j++) m = fmaxf(m, alpha[p][j] + end_t[j]);
    float s = 0.f;
    for (int j = 0; j < 20; j++) s += __expf(alpha[p][j] + end_t[j] - m);
    float logZ = m + __logf(s);
    atomicAdd(out, -(score - logZ));
  }
}

extern "C" void kernel_launch(void* const* d_in, const int* in_sizes, int n_in,
                              void* d_out, int out_size, void* d_ws, size_t ws_size,
                              hipStream_t stream) {
  const int*   inp     = (const int*)d_in[0];
  const int*   labels  = (const int*)d_in[1];
  const float* emb     = (const float*)d_in[2];
  const float* w_ih    = (const float*)d_in[3];
  const float* w_hh    = (const float*)d_in[4];
  const float* b_ih    = (const float*)d_in[5];
  const float* b_hh    = (const float*)d_in[6];
  const float* W_lin   = (const float*)d_in[7];
  const float* b_lin   = (const float*)d_in[8];
  const float* start_t = (const float*)d_in[9];
  const float* end_t   = (const float*)d_in[10];
  const float* trans   = (const float*)d_in[11];
  float* out = (float*)d_out;
  char* ws = (char*)d_ws;

  unsigned*      g_in_u = (unsigned*)(ws);                     // 67,108,864  (T*B*1024 f16)
  float*         houts  = (float*)(ws + 67108864);             // 33,554,432  (T*B*H f32)
  float*         em     = (float*)(ws + 100663296);            //  2,621,440  (T*B*K f32)
  float*         w_ihT  = (float*)(ws + 103284736);            //  1,228,800  (300x1024 f32)
  unsigned char* W8     = (unsigned char*)(ws + 104513536);    //    262,144  (1024x256 fp8)
  float*         b_comb = (float*)(ws + 104775680);            //      4,096

  prep_kernel<<<512, 256, 0, stream>>>(w_ih, w_hh, b_ih, b_hh, w_ihT, W8, b_comb, out);
  kernelA<<<4096, 256, 0, stream>>>(inp, emb, w_ihT, b_comb, g_in_u);
  kernelB<<<16, 1024, 0, stream>>>((const _Float16*)g_in_u, W8, houts);
  kernelC<<<1024, 256, 0, stream>>>(houts, W_lin, b_lin, em);
  kernelD<<<64, 64, 0, stream>>>(em, labels, start_t, end_t, trans, out);
}

// Round 4
// 1599.485 us; speedup vs baseline: 1.5721x; 1.5721x over previous
//
#include <hip/hip_runtime.h>
#include <math.h>

#define T_ 512
#define B_ 64
#define V_ 50000
#define E_ 300
#define H_ 256
#define K_ 20
#define G4 1024  /* 4*H */

typedef float f4 __attribute__((ext_vector_type(4)));
typedef _Float16 h2_t __attribute__((ext_vector_type(2)));
union U32H2 { unsigned u; h2_t h; };
__device__ __forceinline__ h2_t u2h(unsigned u) { U32H2 x; x.u = u; return x.h; }
__device__ __forceinline__ unsigned h2u(h2_t h) { U32H2 x; x.h = h; return x.u; }

__device__ __forceinline__ float sigf(float x) { return 1.f / (1.f + __expf(-x)); }
__device__ __forceinline__ float tanhfast(float x) { return 1.f - 2.f / (__expf(2.f * x) + 1.f); }

__device__ __forceinline__ unsigned char f32_e4m3(float x) {
  return (unsigned char)(__builtin_amdgcn_cvt_pk_fp8_f32(x, x, 0, false) & 0xff);
}

// ---------------- prep: transpose w_ih, quantize w_hh to fp8 e4m3 (x64), biases, zero out ----
__global__ void prep_kernel(const float* __restrict__ w_ih, const float* __restrict__ w_hh,
                            const float* __restrict__ b_ih, const float* __restrict__ b_hh,
                            float* __restrict__ w_ihT, unsigned char* __restrict__ W8,
                            float* __restrict__ b_comb, float* __restrict__ out) {
  int tid = blockIdx.x * blockDim.x + threadIdx.x;
  int nth = gridDim.x * blockDim.x;
  for (int i = tid; i < E_ * G4; i += nth) {
    int e = i >> 10, row = i & 1023;
    w_ihT[i] = w_ih[row * E_ + e];
  }
  for (int i = tid; i < G4 * H_; i += nth) {
    W8[i] = f32_e4m3(w_hh[i] * 64.f);
  }
  for (int i = tid; i < G4; i += nth) b_comb[i] = b_ih[i] + b_hh[i];
  if (tid == 0) out[0] = 0.f;
}

// ---------------- kernel A: g_in[t][b][row] (f16) = emb[inp[t,b]] @ w_ih^T + b_ih + b_hh ------
__global__ __launch_bounds__(256) void kernelA(const int* __restrict__ inp,
                                               const float* __restrict__ emb,
                                               const float* __restrict__ w_ihT,
                                               const float* __restrict__ b_comb,
                                               unsigned* __restrict__ g_in_u) {
  __shared__ float xs[32][304];
  __shared__ int ridx[32];
  int bm = blockIdx.x >> 2;
  int bn = blockIdx.x & 3;
  int tid = threadIdx.x;
  if (tid < 32) ridx[tid] = inp[bm * 32 + tid];
  __syncthreads();
  for (int i = tid; i < 32 * 75; i += 256) {
    int r = i / 75, c = i % 75;
    float4 v = *(const float4*)(emb + (long)ridx[r] * E_ + c * 4);
    *(float4*)&xs[r][c * 4] = v;
  }
  __syncthreads();
  int cx = tid & 63, ry = tid >> 6;
  int col = bn * 256 + cx * 4;
  f4 acc[8];
#pragma unroll
  for (int r = 0; r < 8; r++) acc[r] = (f4){0.f, 0.f, 0.f, 0.f};
#pragma unroll 4
  for (int e = 0; e < E_; e++) {
    f4 w = *(const f4*)(w_ihT + e * G4 + col);
#pragma unroll
    for (int r = 0; r < 8; r++) {
      acc[r] += w * xs[ry * 8 + r][e];   // packed f32 fma (v_pk_fma_f32)
    }
  }
  f4 bb = *(const f4*)(b_comb + col);
#pragma unroll
  for (int r = 0; r < 8; r++) {
    f4 o = acc[r] + bb;
    h2_t p0, p1;
    p0.x = (_Float16)o.x; p0.y = (_Float16)o.y;
    p1.x = (_Float16)o.z; p1.y = (_Float16)o.w;
    uint2 st; st.x = h2u(p0); st.y = h2u(p1);
    long row = (long)bm * 32 + ry * 8 + r;
    *(uint2*)(g_in_u + ((row * G4 + col) >> 1)) = st;
  }
}

// ---------------- kernel B: sequential LSTM, fp8 MFMA, weights pinned in AGPRs ---------------
// 16 blocks x 1024 threads (16 waves). Block bb owns batches 4bb..4bb+3.
// Wave w owns gate rows 16*(w+16*tau)+col, tau = gates i,f,g,o -> units 16w..16w+15.
// B-fragment col batches broadcast x4 (cb=col&3) so every lane's accs are valid; elementwise
// split across the duplicate column groups: lane handles r = col>>2 only -> each (batch,unit)
// nonlinearity computed exactly once. One barrier per step.
#define WSCALE 64.f
#define HSCALE 16.f
#define DESCALE (1.f / (WSCALE * HSCALE))

__global__ __launch_bounds__(1024, 4) void kernelB(const _Float16* __restrict__ g_in,
                                                   const unsigned char* __restrict__ W8,
                                                   float* __restrict__ houts) {
  int bb = blockIdx.x;
  int tid = threadIdx.x;
  int lane = tid & 63, w = tid >> 6;
  int col = lane & 15, quad = lane >> 4;
  int cb = col & 3;
  int r = col >> 2;

  __shared__ unsigned char h8[2][4 * 272];   // [buf][batch][k-permuted 256 + pad]

  for (int i = tid; i < 2 * 4 * 272; i += 1024) ((unsigned char*)h8)[i] = 0;

  // persistent A-fragments in AGPRs: wf[tau*8+c] = W8[16*(w+16*tau)+col][32c + quad*8 .. +7]
  unsigned long long wf[32];
#pragma unroll
  for (int tc = 0; tc < 32; tc++) {
    int tau = tc >> 3, c = tc & 7;
    wf[tc] = *(const unsigned long long*)(W8 + (unsigned)(16 * (w + 16 * tau) + col) * 256 + quad * 8 + 32 * c);
  }
#pragma unroll
  for (int tc = 0; tc < 32; tc++) asm volatile("" : "+a"(wf[tc]));  // pin in AGPRs: no remat, off the arch-VGPR budget

  int myk = 16 * w + 4 * quad + r;            // this lane's hidden unit
  int batch = 4 * bb + cb;                    // this lane's batch
  // h8 byte slot for unit myk, batch cb (B-fragment k permutation):
  int myslot = cb * 272 + ((myk >> 3) & 3) * 64 + 16 * (myk >> 6) + 8 * ((myk >> 5) & 1) + (myk & 7);
  const unsigned char* bp0 = &h8[0][cb * 272 + quad * 64];
  const unsigned char* bp1 = &h8[1][cb * 272 + quad * 64];
  const _Float16* gbase = g_in + (long)batch * G4 + myk;

  float cst = 0.f;

  // preload g for t=0 (4 gate inputs for (batch, myk))
  float gi_ = (float)gbase[0];
  float gf_ = (float)gbase[256];
  float gg_ = (float)gbase[512];
  float go_ = (float)gbase[768];

  __syncthreads();

  for (int t = 0; t < T_; t++) {
    const unsigned char* bptr = (t & 1) ? bp1 : bp0;
    f4 acc0 = {0.f, 0.f, 0.f, 0.f}, acc1 = acc0, acc2 = acc0, acc3 = acc0;
#pragma unroll
    for (int i = 0; i < 4; i++) {
      ulonglong2 bv = *(const ulonglong2*)(bptr + i * 16);
      long long b0 = (long long)bv.x;
      long long b1 = (long long)bv.y;
      acc0 = __builtin_amdgcn_mfma_f32_16x16x32_fp8_fp8((long long)wf[0 * 8 + 2 * i], b0, acc0, 0, 0, 0);
      acc1 = __builtin_amdgcn_mfma_f32_16x16x32_fp8_fp8((long long)wf[1 * 8 + 2 * i], b0, acc1, 0, 0, 0);
      acc2 = __builtin_amdgcn_mfma_f32_16x16x32_fp8_fp8((long long)wf[2 * 8 + 2 * i], b0, acc2, 0, 0, 0);
      acc3 = __builtin_amdgcn_mfma_f32_16x16x32_fp8_fp8((long long)wf[3 * 8 + 2 * i], b0, acc3, 0, 0, 0);
      acc0 = __builtin_amdgcn_mfma_f32_16x16x32_fp8_fp8((long long)wf[0 * 8 + 2 * i + 1], b1, acc0, 0, 0, 0);
      acc1 = __builtin_amdgcn_mfma_f32_16x16x32_fp8_fp8((long long)wf[1 * 8 + 2 * i + 1], b1, acc1, 0, 0, 0);
      acc2 = __builtin_amdgcn_mfma_f32_16x16x32_fp8_fp8((long long)wf[2 * 8 + 2 * i + 1], b1, acc2, 0, 0, 0);
      acc3 = __builtin_amdgcn_mfma_f32_16x16x32_fp8_fp8((long long)wf[3 * 8 + 2 * i + 1], b1, acc3, 0, 0, 0);
    }
    // prefetch next step's g while MFMAs drain
    int tn = (t + 1 < T_) ? (t + 1) : t;
    const _Float16* gp = gbase + (long)tn * B_ * G4;
    float ngi = (float)gp[0];
    float ngf = (float)gp[256];
    float ngg = (float)gp[512];
    float ngo = (float)gp[768];

    // elementwise: this lane's single (batch, unit) = row r of its accs
    float gi = acc0[r] * DESCALE + gi_;
    float gf = acc1[r] * DESCALE + gf_;
    float gg = acc2[r] * DESCALE + gg_;
    float go = acc3[r] * DESCALE + go_;
    cst = sigf(gf) * cst + sigf(gi) * tanhfast(gg);
    float h = sigf(go) * tanhfast(cst);
    h8[1 - (t & 1)][myslot] = f32_e4m3(h * HSCALE);
    houts[((long)t * B_ + batch) * H_ + myk] = h;

    gi_ = ngi; gf_ = ngf; gg_ = ngg; go_ = ngo;
    __syncthreads();
  }
}

// ---------------- kernel C: emissions = houts @ W_lin^T + b_lin ------------------------------
__global__ __launch_bounds__(256) void kernelC(const float* __restrict__ houts,
                                               const float* __restrict__ W_lin,
                                               const float* __restrict__ b_lin,
                                               float* __restrict__ em) {
  __shared__ float hs[32][260];
  __shared__ float wl[20][260];
  __shared__ float bl[20];
  int bm = blockIdx.x;
  int tid = threadIdx.x;
  for (int i = tid; i < 32 * 64; i += 256) {
    int r = i >> 6, c = i & 63;
    *(float4*)&hs[r][c * 4] = *(const float4*)(houts + ((long)bm * 32 + r) * H_ + c * 4);
  }
  for (int i = tid; i < 20 * 64; i += 256) {
    int k = i >> 6, c = i & 63;
    *(float4*)&wl[k][c * 4] = *(const float4*)(W_lin + k * H_ + c * 4);
  }
  if (tid < 20) bl[tid] = b_lin[tid];
  __syncthreads();
  for (int o = tid; o < 32 * 20; o += 256) {
    int r = o / 20, k = o % 20;
    float s = 0.f;
#pragma unroll 4
    for (int i = 0; i < H_; i++) s += hs[r][i] * wl[k][i];
    em[(long)bm * 32 * K_ + o] = s + bl[k];
  }
}

// ---------------- kernel D: CRF forward DP + gold score + NLL reduction ----------------------
__global__ __launch_bounds__(64) void kernelD(const float* __restrict__ em,
                                              const int* __restrict__ labels,
                                              const float* __restrict__ start_t,
                                              const float* __restrict__ end_t,
                                              const float* __restrict__ trans,
                                              float* __restrict__ out) {
  int b = blockIdx.x;
  int k = threadIdx.x;
  __shared__ float tr[400];
  __shared__ float alpha[2][20];
  for (int i = k; i < 400; i += 64) tr[i] = trans[i];
  float score = 0.f;
  int prevtag = 0;
  if (k == 0) {
    int t0 = labels[b];
    score = start_t[t0] + em[b * K_ + t0];
    prevtag = t0;
  }
  if (k < K_) alpha[0][k] = start_t[k] + em[b * K_ + k];
  __syncthreads();
  int p = 0;
  for (int t = 1; t < T_; t++) {
    const float* emrow = em + ((long)t * B_ + b) * K_;
    if (k < K_) {
      float v[20];
      float m = -1e30f;
#pragma unroll
      for (int j = 0; j < 20; j++) {
        v[j] = alpha[p][j] + tr[j * 20 + k];
        m = fmaxf(m, v[j]);
      }
      float s = 0.f;
#pragma unroll
      for (int j = 0; j < 20; j++) s += __expf(v[j] - m);
      alpha[1 - p][k] = emrow[k] + m + __logf(s);
    }
    if (k == 0) {
      int tg = labels[t * B_ + b];
      score += tr[prevtag * 20 + tg] + emrow[tg];
      prevtag = tg;
    }
    p ^= 1;
    __syncthreads();
  }
  if (k == 0) {
    score += end_t[prevtag];
    float m = -1e30f;
    for (int j = 0; j < 20; j++) m = fmaxf(m, alpha[p][j] + end_t[j]);
    float s = 0.f;
    for (int j = 0; j < 20; j++) s += __expf(alpha[p][j] + end_t[j] - m);
    float logZ = m + __logf(s);
    atomicAdd(out, -(score - logZ));
  }
}

extern "C" void kernel_launch(void* const* d_in, const int* in_sizes, int n_in,
                              void* d_out, int out_size, void* d_ws, size_t ws_size,
                              hipStream_t stream) {
  const int*   inp     = (const int*)d_in[0];
  const int*   labels  = (const int*)d_in[1];
  const float* emb     = (const float*)d_in[2];
  const float* w_ih    = (const float*)d_in[3];
  const float* w_hh    = (const float*)d_in[4];
  const float* b_ih    = (const float*)d_in[5];
  const float* b_hh    = (const float*)d_in[6];
  const float* W_lin   = (const float*)d_in[7];
  const float* b_lin   = (const float*)d_in[8];
  const float* start_t = (const float*)d_in[9];
  const float* end_t   = (const float*)d_in[10];
  const float* trans   = (const float*)d_in[11];
  float* out = (float*)d_out;
  char* ws = (char*)d_ws;

  unsigned*      g_in_u = (unsigned*)(ws);                     // 67,108,864  (T*B*1024 f16)
  float*         houts  = (float*)(ws + 67108864);             // 33,554,432  (T*B*H f32)
  float*         em     = (float*)(ws + 100663296);            //  2,621,440  (T*B*K f32)
  float*         w_ihT  = (float*)(ws + 103284736);            //  1,228,800  (300x1024 f32)
  unsigned char* W8     = (unsigned char*)(ws + 104513536);    //    262,144  (1024x256 fp8)
  float*         b_comb = (float*)(ws + 104775680);            //      4,096

  prep_kernel<<<512, 256, 0, stream>>>(w_ih, w_hh, b_ih, b_hh, w_ihT, W8, b_comb, out);
  kernelA<<<4096, 256, 0, stream>>>(inp, emb, w_ihT, b_comb, g_in_u);
  kernelB<<<16, 1024, 0, stream>>>((const _Float16*)g_in_u, W8, houts);
  kernelC<<<1024, 256, 0, stream>>>(houts, W_lin, b_lin, em);
  kernelD<<<64, 64, 0, stream>>>(em, labels, start_t, end_t, trans, out);
}